// Round 1
// baseline (840.068 us; speedup 1.0000x reference)
//
#include <hip/hip_runtime.h>
#include <math.h>

// Problem constants (B=2, T=512 -> N=1024 tokens)
constexpr int N    = 1024;
constexpr int DIM  = 512;
constexpr int HID  = 2048;
constexpr int NE   = 64;

// ---------------------------------------------------------------------------
// Gating: logits = (x @ emb^T)/sqrt(din); softmax; gate=max prob; idx=argmax.
// f64 accumulation so argmax matches the true (numpy) argmax.
// One block per token, 256 threads: 4 threads per expert, each does din/4.
// ---------------------------------------------------------------------------
template <int DIN>
__global__ __launch_bounds__(256) void gating_kernel(
    const float* __restrict__ X, const float* __restrict__ emb,
    float* __restrict__ gate, int* __restrict__ idx, int* __restrict__ cnt)
{
    const int n   = blockIdx.x;
    const int tid = threadIdx.x;

    __shared__ float  xs[DIN];
    __shared__ double red[256];

    // stage token row
    const float4* xr  = (const float4*)(X + (size_t)n * DIN);
    float4*       xs4 = (float4*)xs;
    for (int i = tid; i < DIN / 4; i += 256) xs4[i] = xr[i];
    __syncthreads();

    const int e    = tid >> 2;
    const int part = tid & 3;
    constexpr int SEG = DIN / 4;

    const float* w  = emb + (size_t)e * DIN + part * SEG;
    const float* xv = xs + part * SEG;

    double acc = 0.0;
    #pragma unroll 4
    for (int i = 0; i < SEG; i++) acc += (double)xv[i] * (double)w[i];

    red[tid] = acc;
    __syncthreads();

    if (tid < 64) {  // wave 0, all 64 lanes active
        double s = red[tid * 4] + red[tid * 4 + 1] + red[tid * 4 + 2] + red[tid * 4 + 3];
        float  l = (float)(s / sqrt((double)DIN));

        // wave argmax (tie -> lower index, matching jnp.argmax)
        float m = l; int mi = tid;
        #pragma unroll
        for (int off = 32; off > 0; off >>= 1) {
            float om = __shfl_down(m, off);
            int   oi = __shfl_down(mi, off);
            if (om > m || (om == m && oi < mi)) { m = om; mi = oi; }
        }
        m  = __shfl(m, 0);
        mi = __shfl(mi, 0);

        float p = expf(l - m);
        float ssum = p;
        #pragma unroll
        for (int off = 32; off > 0; off >>= 1) ssum += __shfl_down(ssum, off);

        if (tid == 0) {
            gate[n] = 1.0f / ssum;   // exp(l_max - m)/sum = 1/sum
            idx[n]  = mi;
            atomicAdd(&cnt[mi], 1);
        }
    }
}

// ---------------------------------------------------------------------------
// Tiny exclusive scan over 64 expert counts.
// ---------------------------------------------------------------------------
__global__ void scan_kernel(const int* __restrict__ cnt, int* __restrict__ off)
{
    if (threadIdx.x == 0) {
        int s = 0;
        for (int e = 0; e < NE; e++) { off[e] = s; s += cnt[e]; }
    }
}

// ---------------------------------------------------------------------------
// Scatter token ids into per-expert buckets.
// ---------------------------------------------------------------------------
__global__ __launch_bounds__(256) void scatter_kernel(
    const int* __restrict__ idx, const int* __restrict__ off,
    int* __restrict__ cur, int* __restrict__ bucket)
{
    const int n = blockIdx.x * 256 + threadIdx.x;
    const int e = idx[n];
    const int p = atomicAdd(&cur[e], 1);
    bucket[off[e] + p] = n;
}

// ---------------------------------------------------------------------------
// Grouped GEMM layer 1 + gate scale + exact GELU.
// grid = (NE, HID/256). Block handles expert e, 256 HID columns (1/thread).
// Tokens of the expert staged 32 at a time into 64 KB LDS.
// W1 ([E][DIM][HID]) is read exactly once across the grid.
// ---------------------------------------------------------------------------
__global__ __launch_bounds__(256) void moe_gemm1(
    const float* __restrict__ X,  const float* __restrict__ W1,
    const float* __restrict__ b1, const float* __restrict__ gate,
    const int* __restrict__ cnt,  const int* __restrict__ off,
    const int* __restrict__ bucket, float* __restrict__ H)
{
    const int e   = blockIdx.x;
    const int c   = blockIdx.y * 256 + threadIdx.x;
    const int mt  = cnt[e];
    const int base = off[e];

    __shared__ float xs[32][DIM];   // 64 KB

    const float* Wc   = W1 + (size_t)e * DIM * HID + c;  // stride HID over d
    const float  bias = b1[(size_t)e * HID + c];

    for (int chunk = 0; chunk < mt; chunk += 32) {
        const int m = min(32, mt - chunk);

        for (int i = threadIdx.x; i < m * (DIM / 4); i += 256) {
            const int t = i / (DIM / 4), j = i % (DIM / 4);
            ((float4*)xs[t])[j] =
                ((const float4*)(X + (size_t)bucket[base + chunk + t] * DIM))[j];
        }
        __syncthreads();

        float acc[32];
        #pragma unroll
        for (int t = 0; t < 32; t++) acc[t] = 0.f;

        #pragma unroll 2
        for (int d = 0; d < DIM; d += 4) {
            const float w0 = Wc[(size_t)(d + 0) * HID];
            const float w1 = Wc[(size_t)(d + 1) * HID];
            const float w2 = Wc[(size_t)(d + 2) * HID];
            const float w3 = Wc[(size_t)(d + 3) * HID];
            #pragma unroll
            for (int t = 0; t < 32; t++) {
                const float4 xv = *(const float4*)&xs[t][d];
                acc[t] = fmaf(xv.x, w0, acc[t]);
                acc[t] = fmaf(xv.y, w1, acc[t]);
                acc[t] = fmaf(xv.z, w2, acc[t]);
                acc[t] = fmaf(xv.w, w3, acc[t]);
            }
        }

        for (int t = 0; t < m; t++) {
            const int   tok = bucket[base + chunk + t];
            const float v   = gate[tok] * (acc[t] + bias);
            H[(size_t)tok * HID + c] = 0.5f * v * (1.0f + erff(v * 0.70710678118654752f));
        }
        __syncthreads();
    }
}

// ---------------------------------------------------------------------------
// Grouped GEMM layer 2 + gate scale, 4-way split over the reduction dim
// (atomicAdd into zero-initialized d_out). grid = (NE, DIM/256, 4).
// W2 ([E][HID][DIM]) is read exactly once across the grid.
// ---------------------------------------------------------------------------
__global__ __launch_bounds__(256) void moe_gemm2(
    const float* __restrict__ H,  const float* __restrict__ W2,
    const float* __restrict__ b2, const float* __restrict__ gate,
    const int* __restrict__ cnt,  const int* __restrict__ off,
    const int* __restrict__ bucket, float* __restrict__ out)
{
    const int e    = blockIdx.x;
    const int c    = blockIdx.y * 256 + threadIdx.x;   // 0..511
    const int d0   = blockIdx.z * 512;                 // reduction slice
    const int mt   = cnt[e];
    const int base = off[e];

    __shared__ float xs[32][512];   // 64 KB (token rows, this d-slice)

    const float* Wc   = W2 + (size_t)e * HID * DIM + (size_t)d0 * DIM + c;
    const float  bias = (blockIdx.z == 0) ? b2[(size_t)e * DIM + c] : 0.f;

    for (int chunk = 0; chunk < mt; chunk += 32) {
        const int m = min(32, mt - chunk);

        for (int i = threadIdx.x; i < m * 128; i += 256) {
            const int t = i >> 7, j = i & 127;
            ((float4*)xs[t])[j] =
                ((const float4*)(H + (size_t)bucket[base + chunk + t] * HID + d0))[j];
        }
        __syncthreads();

        float acc[32];
        #pragma unroll
        for (int t = 0; t < 32; t++) acc[t] = 0.f;

        #pragma unroll 2
        for (int d = 0; d < 512; d += 4) {
            const float w0 = Wc[(size_t)(d + 0) * DIM];
            const float w1 = Wc[(size_t)(d + 1) * DIM];
            const float w2 = Wc[(size_t)(d + 2) * DIM];
            const float w3 = Wc[(size_t)(d + 3) * DIM];
            #pragma unroll
            for (int t = 0; t < 32; t++) {
                const float4 xv = *(const float4*)&xs[t][d];
                acc[t] = fmaf(xv.x, w0, acc[t]);
                acc[t] = fmaf(xv.y, w1, acc[t]);
                acc[t] = fmaf(xv.z, w2, acc[t]);
                acc[t] = fmaf(xv.w, w3, acc[t]);
            }
        }

        for (int t = 0; t < m; t++) {
            const int tok = bucket[base + chunk + t];
            atomicAdd(&out[(size_t)tok * DIM + c], gate[tok] * (acc[t] + bias));
        }
        __syncthreads();
    }
}

// ---------------------------------------------------------------------------
extern "C" void kernel_launch(void* const* d_in, const int* in_sizes, int n_in,
                              void* d_out, int out_size, void* d_ws, size_t ws_size,
                              hipStream_t stream)
{
    const float* x    = (const float*)d_in[0];
    const float* emb1 = (const float*)d_in[1];
    const float* W1   = (const float*)d_in[2];
    const float* b1   = (const float*)d_in[3];
    const float* emb2 = (const float*)d_in[4];
    const float* W2   = (const float*)d_in[5];
    const float* b2   = (const float*)d_in[6];
    float* out = (float*)d_out;

    // workspace layout (~8.03 MB)
    float* H      = (float*)d_ws;               // N*HID
    float* gate1  = H + (size_t)N * HID;        // N
    float* gate2  = gate1 + N;                  // N
    int*   idx1   = (int*)(gate2 + N);          // N
    int*   idx2   = idx1 + N;                   // N
    int*   bucket1 = idx2 + N;                  // N
    int*   bucket2 = bucket1 + N;               // N
    int*   cnt1   = bucket2 + N;                // 64 each, contiguous below
    int*   off1   = cnt1 + NE;
    int*   cur1   = off1 + NE;
    int*   cnt2   = cur1 + NE;
    int*   off2   = cnt2 + NE;
    int*   cur2   = off2 + NE;

    hipMemsetAsync(cnt1, 0, 6 * NE * sizeof(int), stream);
    hipMemsetAsync(out, 0, (size_t)N * DIM * sizeof(float), stream);

    // layer 1
    gating_kernel<DIM><<<N, 256, 0, stream>>>(x, emb1, gate1, idx1, cnt1);
    scan_kernel<<<1, 64, 0, stream>>>(cnt1, off1);
    scatter_kernel<<<N / 256, 256, 0, stream>>>(idx1, off1, cur1, bucket1);
    moe_gemm1<<<dim3(NE, HID / 256), 256, 0, stream>>>(x, W1, b1, gate1, cnt1, off1,
                                                       bucket1, H);
    // layer 2
    gating_kernel<HID><<<N, 256, 0, stream>>>(H, emb2, gate2, idx2, cnt2);
    scan_kernel<<<1, 64, 0, stream>>>(cnt2, off2);
    scatter_kernel<<<N / 256, 256, 0, stream>>>(idx2, off2, cur2, bucket2);
    moe_gemm2<<<dim3(NE, DIM / 256, 4), 256, 0, stream>>>(H, W2, b2, gate2, cnt2, off2,
                                                          bucket2, out);
}

// Round 2
// 730.799 us; speedup vs baseline: 1.1495x; 1.1495x over previous
//
#include <hip/hip_runtime.h>
#include <math.h>

// Problem constants (B=2, T=512 -> N=1024 tokens)
constexpr int N    = 1024;
constexpr int DIM  = 512;
constexpr int HID  = 2048;
constexpr int NE   = 64;

__device__ inline void fma4(float4& a, float s, const float4& w) {
    a.x = fmaf(s, w.x, a.x);
    a.y = fmaf(s, w.y, a.y);
    a.z = fmaf(s, w.z, a.z);
    a.w = fmaf(s, w.w, a.w);
}

// ---------------------------------------------------------------------------
// Gating: logits = (x @ emb^T)/sqrt(din); softmax; gate=max prob; idx=argmax.
// f64 accumulation so argmax matches the true argmax. 4 tokens per block
// (amortizes emb re-reads 4x). 256 threads: 4 threads per expert.
// ---------------------------------------------------------------------------
template <int DIN>
__global__ __launch_bounds__(256) void gating_kernel(
    const float* __restrict__ X, const float* __restrict__ emb,
    float* __restrict__ gate, int* __restrict__ idx, int* __restrict__ cnt)
{
    constexpr int TPB = 4;
    const int n0  = blockIdx.x * TPB;
    const int tid = threadIdx.x;

    __shared__ float  xs[TPB][DIN];
    __shared__ double red[256];

    for (int i = tid; i < TPB * (DIN / 4); i += 256) {
        const int tk = i / (DIN / 4), j = i % (DIN / 4);
        ((float4*)xs[tk])[j] = ((const float4*)(X + (size_t)(n0 + tk) * DIN))[j];
    }
    __syncthreads();

    const int e    = tid >> 2;
    const int part = tid & 3;
    constexpr int SEG = DIN / 4;

    const float4* w4 = (const float4*)(emb + (size_t)e * DIN + part * SEG);
    double acc[TPB] = {0.0, 0.0, 0.0, 0.0};

    for (int i = 0; i < SEG / 4; i++) {
        const float4 wv = w4[i];
        #pragma unroll
        for (int tk = 0; tk < TPB; tk++) {
            const float4 xv = ((const float4*)(xs[tk] + part * SEG))[i];
            acc[tk] += (double)xv.x * (double)wv.x + (double)xv.y * (double)wv.y
                     + (double)xv.z * (double)wv.z + (double)xv.w * (double)wv.w;
        }
    }

    for (int tk = 0; tk < TPB; tk++) {
        red[tid] = acc[tk];
        __syncthreads();
        if (tid < 64) {  // wave 0
            double s = red[tid * 4] + red[tid * 4 + 1] + red[tid * 4 + 2] + red[tid * 4 + 3];
            float  l = (float)(s / sqrt((double)DIN));

            float m = l; int mi = tid;
            #pragma unroll
            for (int off = 32; off > 0; off >>= 1) {
                float om = __shfl_down(m, off);
                int   oi = __shfl_down(mi, off);
                if (om > m || (om == m && oi < mi)) { m = om; mi = oi; }
            }
            m  = __shfl(m, 0);
            mi = __shfl(mi, 0);

            float p = expf(l - m);
            float ss = p;
            #pragma unroll
            for (int off = 32; off > 0; off >>= 1) ss += __shfl_down(ss, off);

            if (tid == 0) {
                gate[n0 + tk] = 1.0f / ss;
                idx[n0 + tk]  = mi;
                atomicAdd(&cnt[mi], 1);
            }
        }
        __syncthreads();
    }
}

// ---------------------------------------------------------------------------
__global__ void scan_kernel(const int* __restrict__ cnt, int* __restrict__ off)
{
    if (threadIdx.x == 0) {
        int s = 0;
        for (int e = 0; e < NE; e++) { off[e] = s; s += cnt[e]; }
    }
}

__global__ __launch_bounds__(256) void scatter_kernel(
    const int* __restrict__ idx, const int* __restrict__ off,
    int* __restrict__ cur, int* __restrict__ bucket)
{
    const int n = blockIdx.x * 256 + threadIdx.x;
    const int e = idx[n];
    const int p = atomicAdd(&cur[e], 1);
    bucket[off[e] + p] = n;
}

// ---------------------------------------------------------------------------
// Grouped GEMM layer 1 + gate scale + exact GELU.
// grid = (NE, HID/512). Block: 2 token-halves x 128 col-threads.
// Thread tile: 16 tokens x 4 consecutive cols (float4 W loads, float4 acc).
// W1 [E][DIM][HID] streamed once (2nd half's loads hit L1).
// ---------------------------------------------------------------------------
__global__ __launch_bounds__(256) void moe_gemm1(
    const float* __restrict__ X,  const float* __restrict__ W1,
    const float* __restrict__ b1, const float* __restrict__ gate,
    const int* __restrict__ cnt,  const int* __restrict__ off,
    const int* __restrict__ bucket, float* __restrict__ H)
{
    const int e    = blockIdx.x;
    const int mt   = cnt[e];
    if (mt == 0) return;
    const int base = off[e];
    const int tid  = threadIdx.x;
    const int half = tid >> 7;           // token half (0/1)
    const int c    = blockIdx.y * 512 + (tid & 127) * 4;

    __shared__ float xs[32][DIM];        // 64 KB

    const float* Wc = W1 + (size_t)e * DIM * HID + c;
    const float4 bias4 = *(const float4*)(b1 + (size_t)e * HID + c);

    for (int chunk = 0; chunk < mt; chunk += 32) {
        const int m = min(32, mt - chunk);

        for (int i = tid; i < m * (DIM / 4); i += 256) {
            const int t = i >> 7, j = i & 127;
            ((float4*)xs[t])[j] =
                ((const float4*)(X + (size_t)bucket[base + chunk + t] * DIM))[j];
        }
        __syncthreads();

        float4 acc[16];
        #pragma unroll
        for (int t = 0; t < 16; t++) acc[t] = make_float4(0.f, 0.f, 0.f, 0.f);

        #pragma unroll 4
        for (int dg = 0; dg < DIM / 4; dg++) {
            float4 wr[4];
            const float* wq = Wc + (size_t)dg * 4 * HID;
            #pragma unroll
            for (int r = 0; r < 4; r++)
                wr[r] = *(const float4*)(wq + (size_t)r * HID);
            #pragma unroll
            for (int t = 0; t < 16; t++) {
                const float4 xv = *(const float4*)&xs[half * 16 + t][dg * 4];
                fma4(acc[t], xv.x, wr[0]);
                fma4(acc[t], xv.y, wr[1]);
                fma4(acc[t], xv.z, wr[2]);
                fma4(acc[t], xv.w, wr[3]);
            }
        }

        #pragma unroll
        for (int t = 0; t < 16; t++) {
            const int ti = chunk + half * 16 + t;
            if (ti < mt) {
                const int   tok = bucket[base + ti];
                const float g   = gate[tok];
                float4 v;
                v.x = g * (acc[t].x + bias4.x);
                v.y = g * (acc[t].y + bias4.y);
                v.z = g * (acc[t].z + bias4.z);
                v.w = g * (acc[t].w + bias4.w);
                v.x = 0.5f * v.x * (1.0f + erff(v.x * 0.70710678118654752f));
                v.y = 0.5f * v.y * (1.0f + erff(v.y * 0.70710678118654752f));
                v.z = 0.5f * v.z * (1.0f + erff(v.z * 0.70710678118654752f));
                v.w = 0.5f * v.w * (1.0f + erff(v.w * 0.70710678118654752f));
                *(float4*)(H + (size_t)tok * HID + c) = v;
            }
        }
        __syncthreads();
    }
}

// ---------------------------------------------------------------------------
// Grouped GEMM layer 2 + gate scale. 4-way K-split (z = blockIdx.y),
// atomicAdd into zeroed out. grid = (NE, 4). Thread tile 16 tok x 4 cols.
// W2 [E][HID][DIM] streamed once.
// ---------------------------------------------------------------------------
__global__ __launch_bounds__(256) void moe_gemm2(
    const float* __restrict__ Hm, const float* __restrict__ W2,
    const float* __restrict__ b2, const float* __restrict__ gate,
    const int* __restrict__ cnt,  const int* __restrict__ off,
    const int* __restrict__ bucket, float* __restrict__ out)
{
    const int e    = blockIdx.x;
    const int z    = blockIdx.y;         // K-slice, 512 rows each
    const int mt   = cnt[e];
    if (mt == 0) return;
    const int base = off[e];
    const int tid  = threadIdx.x;
    const int half = tid >> 7;
    const int c    = (tid & 127) * 4;    // DIM = 512 -> one col tile

    __shared__ float xs[32][512];        // 64 KB (K-slice of H rows)

    const float* Wc = W2 + (size_t)e * HID * DIM + (size_t)z * 512 * DIM + c;
    float4 bias4 = make_float4(0.f, 0.f, 0.f, 0.f);
    if (z == 0) bias4 = *(const float4*)(b2 + (size_t)e * DIM + c);

    for (int chunk = 0; chunk < mt; chunk += 32) {
        const int m = min(32, mt - chunk);

        for (int i = tid; i < m * 128; i += 256) {
            const int t = i >> 7, j = i & 127;
            ((float4*)xs[t])[j] =
                ((const float4*)(Hm + (size_t)bucket[base + chunk + t] * HID + z * 512))[j];
        }
        __syncthreads();

        float4 acc[16];
        #pragma unroll
        for (int t = 0; t < 16; t++) acc[t] = make_float4(0.f, 0.f, 0.f, 0.f);

        #pragma unroll 4
        for (int dg = 0; dg < 128; dg++) {
            float4 wr[4];
            const float* wq = Wc + (size_t)dg * 4 * DIM;
            #pragma unroll
            for (int r = 0; r < 4; r++)
                wr[r] = *(const float4*)(wq + (size_t)r * DIM);
            #pragma unroll
            for (int t = 0; t < 16; t++) {
                const float4 xv = *(const float4*)&xs[half * 16 + t][dg * 4];
                fma4(acc[t], xv.x, wr[0]);
                fma4(acc[t], xv.y, wr[1]);
                fma4(acc[t], xv.z, wr[2]);
                fma4(acc[t], xv.w, wr[3]);
            }
        }

        #pragma unroll
        for (int t = 0; t < 16; t++) {
            const int ti = chunk + half * 16 + t;
            if (ti < mt) {
                const int   tok = bucket[base + ti];
                const float g   = gate[tok];
                float* o = out + (size_t)tok * DIM + c;
                atomicAdd(o + 0, g * (acc[t].x + bias4.x));
                atomicAdd(o + 1, g * (acc[t].y + bias4.y));
                atomicAdd(o + 2, g * (acc[t].z + bias4.z));
                atomicAdd(o + 3, g * (acc[t].w + bias4.w));
            }
        }
        __syncthreads();
    }
}

// ---------------------------------------------------------------------------
extern "C" void kernel_launch(void* const* d_in, const int* in_sizes, int n_in,
                              void* d_out, int out_size, void* d_ws, size_t ws_size,
                              hipStream_t stream)
{
    const float* x    = (const float*)d_in[0];
    const float* emb1 = (const float*)d_in[1];
    const float* W1   = (const float*)d_in[2];
    const float* b1   = (const float*)d_in[3];
    const float* emb2 = (const float*)d_in[4];
    const float* W2   = (const float*)d_in[5];
    const float* b2   = (const float*)d_in[6];
    float* out = (float*)d_out;

    // workspace layout (~8.03 MB)
    float* H       = (float*)d_ws;              // N*HID
    float* gate1   = H + (size_t)N * HID;       // N
    float* gate2   = gate1 + N;                 // N
    int*   idx1    = (int*)(gate2 + N);         // N
    int*   idx2    = idx1 + N;                  // N
    int*   bucket1 = idx2 + N;                  // N
    int*   bucket2 = bucket1 + N;               // N
    int*   cnt1    = bucket2 + N;               // 6*NE contiguous ints below
    int*   off1    = cnt1 + NE;
    int*   cur1    = off1 + NE;
    int*   cnt2    = cur1 + NE;
    int*   off2    = cnt2 + NE;
    int*   cur2    = off2 + NE;

    hipMemsetAsync(cnt1, 0, 6 * NE * sizeof(int), stream);
    hipMemsetAsync(out, 0, (size_t)N * DIM * sizeof(float), stream);

    // layer 1
    gating_kernel<DIM><<<N / 4, 256, 0, stream>>>(x, emb1, gate1, idx1, cnt1);
    scan_kernel<<<1, 64, 0, stream>>>(cnt1, off1);
    scatter_kernel<<<N / 256, 256, 0, stream>>>(idx1, off1, cur1, bucket1);
    moe_gemm1<<<dim3(NE, HID / 512), 256, 0, stream>>>(x, W1, b1, gate1, cnt1, off1,
                                                       bucket1, H);
    // layer 2
    gating_kernel<HID><<<N / 4, 256, 0, stream>>>(H, emb2, gate2, idx2, cnt2);
    scan_kernel<<<1, 64, 0, stream>>>(cnt2, off2);
    scatter_kernel<<<N / 256, 256, 0, stream>>>(idx2, off2, cur2, bucket2);
    moe_gemm2<<<dim3(NE, 4), 256, 0, stream>>>(H, W2, b2, gate2, cnt2, off2,
                                               bucket2, out);
}